// Round 1
// baseline (94.434 us; speedup 1.0000x reference)
//
#include <hip/hip_runtime.h>

// CARAFE upsample, N=2 C=256 H=W=128, K=5 S=2 G=1, f32 in/out.
// One thread owns one source pixel (n,h,w) -> the 2x2 output quad (2h..,2w..),
// holds the quad's 100 mask weights in registers (invariant over channels),
// and loops over a 32-channel chunk loading 25 features per channel.

namespace {
constexpr int N_ = 2, C_ = 256, H_ = 128, W_ = 128;
constexpr int K_ = 5, S_ = 2, PAD_ = 2;
constexpr int SH_ = H_ * S_, SW_ = W_ * S_;      // 256, 256
constexpr int CPB = 32;                          // channels per block
constexpr int TPB = 256;
constexpr int BLOCKS_PER_IMG = (H_ * W_) / TPB;  // 64
}

__global__ __launch_bounds__(TPB) void carafe_kernel(
    const float* __restrict__ feat,
    const float* __restrict__ masks,
    float* __restrict__ out)
{
    const int n  = blockIdx.x / BLOCKS_PER_IMG;                 // block-uniform
    const int p  = (blockIdx.x % BLOCKS_PER_IMG) * TPB + threadIdx.x;
    const int h  = p >> 7;              // p / W_
    const int w  = p & (W_ - 1);
    const int c0 = blockIdx.y * CPB;

    const int oh0 = h * S_, ow0 = w * S_;

    // ---- 100 mask weights for the 2x2 quad, float2 (two output cols) loads
    float mtl[25], mtr[25], mbl[25], mbr[25];
    {
        const float* mb = masks + ((size_t)n * 25) * (SH_ * SW_)
                                + (size_t)oh0 * SW_ + ow0;
#pragma unroll
        for (int k = 0; k < 25; ++k) {
            float2 t = *(const float2*)(mb + (size_t)k * (SH_ * SW_));
            float2 b = *(const float2*)(mb + (size_t)k * (SH_ * SW_) + SW_);
            mtl[k] = t.x; mtr[k] = t.y; mbl[k] = b.x; mbr[k] = b.y;
        }
    }

    // ---- per-tap clamped offsets; fold zero-padding into the mask registers
    int off[25];
#pragma unroll
    for (int di = 0; di < K_; ++di) {
#pragma unroll
        for (int dj = 0; dj < K_; ++dj) {
            int y = h + di - PAD_, x = w + dj - PAD_;
            bool valid = ((unsigned)y < (unsigned)H_) && ((unsigned)x < (unsigned)W_);
            int yc = min(max(y, 0), H_ - 1);
            int xc = min(max(x, 0), W_ - 1);
            int k = di * K_ + dj;
            off[k] = yc * W_ + xc;
            if (!valid) { mtl[k] = 0.f; mtr[k] = 0.f; mbl[k] = 0.f; mbr[k] = 0.f; }
        }
    }

    const float* fb = feat + ((size_t)n * C_ + c0) * (H_ * W_);
    float* ob = out + (((size_t)n * C_ + c0) * SH_ + oh0) * SW_ + ow0;

    for (int c = 0; c < CPB; ++c) {
        float f[25];
#pragma unroll
        for (int k = 0; k < 25; ++k) f[k] = fb[off[k]];
        float a0 = 0.f, a1 = 0.f, a2 = 0.f, a3 = 0.f;
#pragma unroll
        for (int k = 0; k < 25; ++k) {
            a0 = fmaf(f[k], mtl[k], a0);
            a1 = fmaf(f[k], mtr[k], a1);
            a2 = fmaf(f[k], mbl[k], a2);
            a3 = fmaf(f[k], mbr[k], a3);
        }
        *(float2*)(ob)       = make_float2(a0, a1);
        *(float2*)(ob + SW_) = make_float2(a2, a3);
        fb += H_ * W_;
        ob += (size_t)SH_ * SW_;
    }
}

extern "C" void kernel_launch(void* const* d_in, const int* in_sizes, int n_in,
                              void* d_out, int out_size, void* d_ws, size_t ws_size,
                              hipStream_t stream) {
    const float* feat  = (const float*)d_in[0];
    const float* masks = (const float*)d_in[1];
    float* out = (float*)d_out;
    dim3 grid(N_ * BLOCKS_PER_IMG, C_ / CPB);   // (128, 8) = 1024 blocks
    carafe_kernel<<<grid, dim3(TPB), 0, stream>>>(feat, masks, out);
}

// Round 3
// 58.757 us; speedup vs baseline: 1.6072x; 1.6072x over previous
//
#include <hip/hip_runtime.h>

// CARAFE upsample, N=2 C=256 H=W=128, K=5 S=2 G=1, f32 in/out.
// R2: R1 with nontemporal-store type fixed (ext_vector float2).
// Double-buffered LDS feature staging. Block = 2 source rows x 128 cols,
// thread owns one source pixel -> its 2x2 output quad; 100 mask weights live
// in registers across a 32-channel loop. Per channel: 4 coalesced global loads
// (next channel, issued early) + 25 conflict-free LDS reads + 100 FMAs.

namespace {
constexpr int N_ = 2, C_ = 256, H_ = 128, W_ = 128;
constexpr int K_ = 5, S_ = 2, PAD_ = 2;
constexpr int SH_ = H_ * S_, SW_ = W_ * S_;          // 256, 256
constexpr int CPB = 32;                              // channels per block
constexpr int TPB = 256;
constexpr int RPB = 2;                               // source rows per block
constexpr int HB_ = H_ / RPB;                        // 64 row-blocks
constexpr int LW  = W_ + 2 * PAD_;                   // 132
constexpr int LROWS = RPB + 2 * PAD_;                // 6
constexpr int LSZ = LROWS * LW;                      // 792
constexpr int NSLOT = (LSZ + TPB - 1) / TPB;         // 4
typedef float v2f __attribute__((ext_vector_type(2)));
}

__global__ __launch_bounds__(TPB) void carafe_kernel(
    const float* __restrict__ feat,
    const float* __restrict__ masks,
    float* __restrict__ out)
{
    __shared__ float lds[2][LSZ];

    const int bx = blockIdx.x;
    const int n  = bx / HB_;                  // block-uniform
    const int h0 = (bx % HB_) * RPB;
    const int t  = threadIdx.x;
    const int hl = t >> 7;                    // 0..1
    const int w  = t & (W_ - 1);
    const int h  = h0 + hl;
    const int c0 = blockIdx.y * CPB;

    // ---- staging descriptors (invariant over channels)
    int  goff[NSLOT];
    bool gval[NSLOT];
#pragma unroll
    for (int s = 0; s < NSLOT; ++s) {
        int idx = s * TPB + t;
        int r  = idx / LW, cc = idx % LW;
        int gy = h0 - PAD_ + r, gx = cc - PAD_;
        bool ok = (idx < LSZ) && ((unsigned)gy < (unsigned)H_) && ((unsigned)gx < (unsigned)W_);
        gval[s] = ok;
        goff[s] = ok ? (gy * W_ + gx) : 0;
    }

    // ---- 100 mask weights for this thread's 2x2 output quad
    float m0[25], m1[25], m2[25], m3[25];
    {
        const float* mb = masks + ((size_t)n * 25) * (SH_ * SW_)
                                + (size_t)(S_ * h) * SW_ + S_ * w;
#pragma unroll
        for (int k = 0; k < 25; ++k) {
            v2f tt = *(const v2f*)(mb + (size_t)k * (SH_ * SW_));
            v2f bb = *(const v2f*)(mb + (size_t)k * (SH_ * SW_) + SW_);
            m0[k] = tt.x; m1[k] = tt.y; m2[k] = bb.x; m3[k] = bb.y;
        }
    }

    const float* fb = feat + ((size_t)n * C_ + c0) * (H_ * W_);
    float*       ob = out + (((size_t)n * C_ + c0) * SH_ + (size_t)(S_ * h)) * SW_ + S_ * w;

    // ---- prologue: stage channel 0 into buffer 0
#pragma unroll
    for (int s = 0; s < NSLOT; ++s) {
        int idx = s * TPB + t;
        if (idx < LSZ) lds[0][idx] = gval[s] ? fb[goff[s]] : 0.f;
    }
    __syncthreads();

    for (int c = 0; c < CPB; ++c) {
        const int cur = c & 1, nxt = cur ^ 1;

        // issue next channel's coalesced loads early (hide HBM/L2 latency under compute)
        float st[NSLOT];
        const float* fn = fb + (size_t)(c + 1) * (H_ * W_);
        if (c + 1 < CPB) {
#pragma unroll
            for (int s = 0; s < NSLOT; ++s) st[s] = gval[s] ? fn[goff[s]] : 0.f;
        }

        // compute current channel from LDS
        const float* L = &lds[cur][0];
        float a0 = 0.f, a1 = 0.f, a2 = 0.f, a3 = 0.f;
#pragma unroll
        for (int di = 0; di < K_; ++di) {
            const float* Lr = L + (hl + di) * LW + w;
            float f0 = Lr[0], f1 = Lr[1], f2 = Lr[2], f3 = Lr[3], f4 = Lr[4];
            const int kb = di * K_;
            a0 = fmaf(f0, m0[kb + 0], a0);
            a1 = fmaf(f0, m1[kb + 0], a1);
            a2 = fmaf(f0, m2[kb + 0], a2);
            a3 = fmaf(f0, m3[kb + 0], a3);
            a0 = fmaf(f1, m0[kb + 1], a0);
            a1 = fmaf(f1, m1[kb + 1], a1);
            a2 = fmaf(f1, m2[kb + 1], a2);
            a3 = fmaf(f1, m3[kb + 1], a3);
            a0 = fmaf(f2, m0[kb + 2], a0);
            a1 = fmaf(f2, m1[kb + 2], a1);
            a2 = fmaf(f2, m2[kb + 2], a2);
            a3 = fmaf(f2, m3[kb + 2], a3);
            a0 = fmaf(f3, m0[kb + 3], a0);
            a1 = fmaf(f3, m1[kb + 3], a1);
            a2 = fmaf(f3, m2[kb + 3], a2);
            a3 = fmaf(f3, m3[kb + 3], a3);
            a0 = fmaf(f4, m0[kb + 4], a0);
            a1 = fmaf(f4, m1[kb + 4], a1);
            a2 = fmaf(f4, m2[kb + 4], a2);
            a3 = fmaf(f4, m3[kb + 4], a3);
        }

        // store the 2x2 quad (streaming, never re-read)
        float* oc = ob + (size_t)c * ((size_t)SH_ * SW_);
        v2f top = {a0, a1}, bot = {a2, a3};
        __builtin_nontemporal_store(top, (v2f*)oc);
        __builtin_nontemporal_store(bot, (v2f*)(oc + SW_));

        // land the staged next channel, then one barrier
        if (c + 1 < CPB) {
#pragma unroll
            for (int s = 0; s < NSLOT; ++s) {
                int idx = s * TPB + t;
                if (idx < LSZ) lds[nxt][idx] = st[s];
            }
        }
        __syncthreads();
    }
}

extern "C" void kernel_launch(void* const* d_in, const int* in_sizes, int n_in,
                              void* d_out, int out_size, void* d_ws, size_t ws_size,
                              hipStream_t stream) {
    const float* feat  = (const float*)d_in[0];
    const float* masks = (const float*)d_in[1];
    float* out = (float*)d_out;
    dim3 grid(N_ * HB_, C_ / CPB);            // (128, 8) = 1024 blocks
    carafe_kernel<<<grid, dim3(TPB), 0, stream>>>(feat, masks, out);
}

// Round 4
// 57.959 us; speedup vs baseline: 1.6293x; 1.0138x over previous
//
#include <hip/hip_runtime.h>

// CARAFE upsample, N=2 C=256 H=W=128, K=5 S=2 G=1, f32 in/out.
// R3: R2 + __launch_bounds__(256, 2). R2's VGPR_Count=68 proved the compiler
// spilled the 100 mask registers (the whole point of the design) to chase
// occupancy; pinning min-waves/EU=2 raises the VGPR cap to 256 so masks,
// staging regs and accumulators all stay resident. Structure unchanged:
// double-buffered LDS feature tile, 4 coalesced loads + 25 LDS reads +
// 100 FMAs + 2 nontemporal float2 stores per channel.

namespace {
constexpr int N_ = 2, C_ = 256, H_ = 128, W_ = 128;
constexpr int K_ = 5, S_ = 2, PAD_ = 2;
constexpr int SH_ = H_ * S_, SW_ = W_ * S_;          // 256, 256
constexpr int CPB = 32;                              // channels per block
constexpr int TPB = 256;
constexpr int RPB = 2;                               // source rows per block
constexpr int HB_ = H_ / RPB;                        // 64 row-blocks
constexpr int LW  = W_ + 2 * PAD_;                   // 132
constexpr int LROWS = RPB + 2 * PAD_;                // 6
constexpr int LSZ = LROWS * LW;                      // 792
constexpr int NSLOT = (LSZ + TPB - 1) / TPB;         // 4
typedef float v2f __attribute__((ext_vector_type(2)));
}

__global__ __launch_bounds__(TPB, 2) void carafe_kernel(
    const float* __restrict__ feat,
    const float* __restrict__ masks,
    float* __restrict__ out)
{
    __shared__ float lds[2][LSZ];

    const int bx = blockIdx.x;
    const int n  = bx / HB_;                  // block-uniform
    const int h0 = (bx % HB_) * RPB;
    const int t  = threadIdx.x;
    const int hl = t >> 7;                    // 0..1
    const int w  = t & (W_ - 1);
    const int h  = h0 + hl;
    const int c0 = blockIdx.y * CPB;

    // ---- staging descriptors (invariant over channels)
    int  goff[NSLOT];
    bool gval[NSLOT];
#pragma unroll
    for (int s = 0; s < NSLOT; ++s) {
        int idx = s * TPB + t;
        int r  = idx / LW, cc = idx % LW;
        int gy = h0 - PAD_ + r, gx = cc - PAD_;
        bool ok = (idx < LSZ) && ((unsigned)gy < (unsigned)H_) && ((unsigned)gx < (unsigned)W_);
        gval[s] = ok;
        goff[s] = ok ? (gy * W_ + gx) : 0;
    }

    // ---- 100 mask weights for this thread's 2x2 output quad (registers!)
    float m0[25], m1[25], m2[25], m3[25];
    {
        const float* mb = masks + ((size_t)n * 25) * (SH_ * SW_)
                                + (size_t)(S_ * h) * SW_ + S_ * w;
#pragma unroll
        for (int k = 0; k < 25; ++k) {
            v2f tt = *(const v2f*)(mb + (size_t)k * (SH_ * SW_));
            v2f bb = *(const v2f*)(mb + (size_t)k * (SH_ * SW_) + SW_);
            m0[k] = tt.x; m1[k] = tt.y; m2[k] = bb.x; m3[k] = bb.y;
        }
    }

    const float* fb = feat + ((size_t)n * C_ + c0) * (H_ * W_);
    float*       ob = out + (((size_t)n * C_ + c0) * SH_ + (size_t)(S_ * h)) * SW_ + S_ * w;

    // ---- prologue: stage channel 0 into buffer 0
#pragma unroll
    for (int s = 0; s < NSLOT; ++s) {
        int idx = s * TPB + t;
        if (idx < LSZ) lds[0][idx] = gval[s] ? fb[goff[s]] : 0.f;
    }
    __syncthreads();

    for (int c = 0; c < CPB; ++c) {
        const int cur = c & 1, nxt = cur ^ 1;

        // issue next channel's coalesced loads early (hide HBM/L2 latency under compute)
        float st[NSLOT];
        const float* fn = fb + (size_t)(c + 1) * (H_ * W_);
        if (c + 1 < CPB) {
#pragma unroll
            for (int s = 0; s < NSLOT; ++s) st[s] = gval[s] ? fn[goff[s]] : 0.f;
        }

        // compute current channel from LDS
        const float* L = &lds[cur][0];
        float a0 = 0.f, a1 = 0.f, a2 = 0.f, a3 = 0.f;
#pragma unroll
        for (int di = 0; di < K_; ++di) {
            const float* Lr = L + (hl + di) * LW + w;
            float f0 = Lr[0], f1 = Lr[1], f2 = Lr[2], f3 = Lr[3], f4 = Lr[4];
            const int kb = di * K_;
            a0 = fmaf(f0, m0[kb + 0], a0);
            a1 = fmaf(f0, m1[kb + 0], a1);
            a2 = fmaf(f0, m2[kb + 0], a2);
            a3 = fmaf(f0, m3[kb + 0], a3);
            a0 = fmaf(f1, m0[kb + 1], a0);
            a1 = fmaf(f1, m1[kb + 1], a1);
            a2 = fmaf(f1, m2[kb + 1], a2);
            a3 = fmaf(f1, m3[kb + 1], a3);
            a0 = fmaf(f2, m0[kb + 2], a0);
            a1 = fmaf(f2, m1[kb + 2], a1);
            a2 = fmaf(f2, m2[kb + 2], a2);
            a3 = fmaf(f2, m3[kb + 2], a3);
            a0 = fmaf(f3, m0[kb + 3], a0);
            a1 = fmaf(f3, m1[kb + 3], a1);
            a2 = fmaf(f3, m2[kb + 3], a2);
            a3 = fmaf(f3, m3[kb + 3], a3);
            a0 = fmaf(f4, m0[kb + 4], a0);
            a1 = fmaf(f4, m1[kb + 4], a1);
            a2 = fmaf(f4, m2[kb + 4], a2);
            a3 = fmaf(f4, m3[kb + 4], a3);
        }

        // store the 2x2 quad (streaming, never re-read)
        float* oc = ob + (size_t)c * ((size_t)SH_ * SW_);
        v2f top = {a0, a1}, bot = {a2, a3};
        __builtin_nontemporal_store(top, (v2f*)oc);
        __builtin_nontemporal_store(bot, (v2f*)(oc + SW_));

        // land the staged next channel, then one barrier
        if (c + 1 < CPB) {
#pragma unroll
            for (int s = 0; s < NSLOT; ++s) {
                int idx = s * TPB + t;
                if (idx < LSZ) lds[nxt][idx] = st[s];
            }
        }
        __syncthreads();
    }
}

extern "C" void kernel_launch(void* const* d_in, const int* in_sizes, int n_in,
                              void* d_out, int out_size, void* d_ws, size_t ws_size,
                              hipStream_t stream) {
    const float* feat  = (const float*)d_in[0];
    const float* masks = (const float*)d_in[1];
    float* out = (float*)d_out;
    dim3 grid(N_ * HB_, C_ / CPB);            // (128, 8) = 1024 blocks
    carafe_kernel<<<grid, dim3(TPB), 0, stream>>>(feat, masks, out);
}

// Round 5
// 57.485 us; speedup vs baseline: 1.6427x; 1.0082x over previous
//
#include <hip/hip_runtime.h>

// CARAFE upsample, N=2 C=256 H=W=128, K=5 S=2 G=1, f32 in/out.
// R4: R3 + asm register-pinning of the 100 mask weights.
// R2/R3 showed VGPR_Count=68: LLVM treats the loop-invariant mask loads as
// rematerializable and sinks them into the channel loop (re-loading ~100
// floats/thread/channel from global). The empty "+v" asm makes each mask
// value an opaque register definition the compiler cannot re-derive from
// memory, forcing them to stay resident across the channel loop.

namespace {
constexpr int N_ = 2, C_ = 256, H_ = 128, W_ = 128;
constexpr int K_ = 5, S_ = 2, PAD_ = 2;
constexpr int SH_ = H_ * S_, SW_ = W_ * S_;          // 256, 256
constexpr int CPB = 32;                              // channels per block
constexpr int TPB = 256;
constexpr int RPB = 2;                               // source rows per block
constexpr int HB_ = H_ / RPB;                        // 64 row-blocks
constexpr int LW  = W_ + 2 * PAD_;                   // 132
constexpr int LROWS = RPB + 2 * PAD_;                // 6
constexpr int LSZ = LROWS * LW;                      // 792
constexpr int NSLOT = (LSZ + TPB - 1) / TPB;         // 4
typedef float v2f __attribute__((ext_vector_type(2)));
}

__global__ __launch_bounds__(TPB, 2) void carafe_kernel(
    const float* __restrict__ feat,
    const float* __restrict__ masks,
    float* __restrict__ out)
{
    __shared__ float lds[2][LSZ];

    const int bx = blockIdx.x;
    const int n  = bx / HB_;                  // block-uniform
    const int h0 = (bx % HB_) * RPB;
    const int t  = threadIdx.x;
    const int hl = t >> 7;                    // 0..1
    const int w  = t & (W_ - 1);
    const int h  = h0 + hl;
    const int c0 = blockIdx.y * CPB;

    // ---- staging descriptors (invariant over channels)
    int  goff[NSLOT];
    bool gval[NSLOT];
#pragma unroll
    for (int s = 0; s < NSLOT; ++s) {
        int idx = s * TPB + t;
        int r  = idx / LW, cc = idx % LW;
        int gy = h0 - PAD_ + r, gx = cc - PAD_;
        bool ok = (idx < LSZ) && ((unsigned)gy < (unsigned)H_) && ((unsigned)gx < (unsigned)W_);
        gval[s] = ok;
        goff[s] = ok ? (gy * W_ + gx) : 0;
    }

    // ---- 100 mask weights for this thread's 2x2 output quad (registers!)
    float m0[25], m1[25], m2[25], m3[25];
    {
        const float* mb = masks + ((size_t)n * 25) * (SH_ * SW_)
                                + (size_t)(S_ * h) * SW_ + S_ * w;
#pragma unroll
        for (int k = 0; k < 25; ++k) {
            v2f tt = *(const v2f*)(mb + (size_t)k * (SH_ * SW_));
            v2f bb = *(const v2f*)(mb + (size_t)k * (SH_ * SW_) + SW_);
            m0[k] = tt.x; m1[k] = tt.y; m2[k] = bb.x; m3[k] = bb.y;
        }
    }
    // Pin masks in VGPRs: opaque definition -> no remat/sink back into the loop.
#pragma unroll
    for (int k = 0; k < 25; ++k) {
        asm volatile("" : "+v"(m0[k]), "+v"(m1[k]), "+v"(m2[k]), "+v"(m3[k]));
    }

    const float* fb = feat + ((size_t)n * C_ + c0) * (H_ * W_);
    float*       ob = out + (((size_t)n * C_ + c0) * SH_ + (size_t)(S_ * h)) * SW_ + S_ * w;

    // ---- prologue: stage channel 0 into buffer 0
#pragma unroll
    for (int s = 0; s < NSLOT; ++s) {
        int idx = s * TPB + t;
        if (idx < LSZ) lds[0][idx] = gval[s] ? fb[goff[s]] : 0.f;
    }
    __syncthreads();

    for (int c = 0; c < CPB; ++c) {
        const int cur = c & 1, nxt = cur ^ 1;

        // issue next channel's coalesced loads early (hide HBM/L2 latency under compute)
        float st[NSLOT];
        const float* fn = fb + (size_t)(c + 1) * (H_ * W_);
        if (c + 1 < CPB) {
#pragma unroll
            for (int s = 0; s < NSLOT; ++s) st[s] = gval[s] ? fn[goff[s]] : 0.f;
        }

        // compute current channel from LDS
        const float* L = &lds[cur][0];
        float a0 = 0.f, a1 = 0.f, a2 = 0.f, a3 = 0.f;
#pragma unroll
        for (int di = 0; di < K_; ++di) {
            const float* Lr = L + (hl + di) * LW + w;
            float f0 = Lr[0], f1 = Lr[1], f2 = Lr[2], f3 = Lr[3], f4 = Lr[4];
            const int kb = di * K_;
            a0 = fmaf(f0, m0[kb + 0], a0);
            a1 = fmaf(f0, m1[kb + 0], a1);
            a2 = fmaf(f0, m2[kb + 0], a2);
            a3 = fmaf(f0, m3[kb + 0], a3);
            a0 = fmaf(f1, m0[kb + 1], a0);
            a1 = fmaf(f1, m1[kb + 1], a1);
            a2 = fmaf(f1, m2[kb + 1], a2);
            a3 = fmaf(f1, m3[kb + 1], a3);
            a0 = fmaf(f2, m0[kb + 2], a0);
            a1 = fmaf(f2, m1[kb + 2], a1);
            a2 = fmaf(f2, m2[kb + 2], a2);
            a3 = fmaf(f2, m3[kb + 2], a3);
            a0 = fmaf(f3, m0[kb + 3], a0);
            a1 = fmaf(f3, m1[kb + 3], a1);
            a2 = fmaf(f3, m2[kb + 3], a2);
            a3 = fmaf(f3, m3[kb + 3], a3);
            a0 = fmaf(f4, m0[kb + 4], a0);
            a1 = fmaf(f4, m1[kb + 4], a1);
            a2 = fmaf(f4, m2[kb + 4], a2);
            a3 = fmaf(f4, m3[kb + 4], a3);
        }

        // store the 2x2 quad (streaming, never re-read)
        float* oc = ob + (size_t)c * ((size_t)SH_ * SW_);
        v2f top = {a0, a1}, bot = {a2, a3};
        __builtin_nontemporal_store(top, (v2f*)oc);
        __builtin_nontemporal_store(bot, (v2f*)(oc + SW_));

        // land the staged next channel, then one barrier
        if (c + 1 < CPB) {
#pragma unroll
            for (int s = 0; s < NSLOT; ++s) {
                int idx = s * TPB + t;
                if (idx < LSZ) lds[nxt][idx] = st[s];
            }
        }
        __syncthreads();
    }
}

extern "C" void kernel_launch(void* const* d_in, const int* in_sizes, int n_in,
                              void* d_out, int out_size, void* d_ws, size_t ws_size,
                              hipStream_t stream) {
    const float* feat  = (const float*)d_in[0];
    const float* masks = (const float*)d_in[1];
    float* out = (float*)d_out;
    dim3 grid(N_ * HB_, C_ / CPB);            // (128, 8) = 1024 blocks
    carafe_kernel<<<grid, dim3(TPB), 0, stream>>>(feat, masks, out);
}

// Round 6
// 56.795 us; speedup vs baseline: 1.6627x; 1.0122x over previous
//
#include <hip/hip_runtime.h>

// CARAFE upsample, N=2 C=256 H=W=128, K=5 S=2 G=1, f32 in/out.
// R5: depth-2 prefetch pipeline. R2-R4 analysis: masks are resident in AGPRs
// (VGPR_Count=68 is arch-VGPRs only; total ~172 regs -> 2 waves/SIMD), and the
// 57µs came from depth-1 staging: loads issued and consumed within one channel
// iteration only cover ~500cyc of compute vs ~900cyc HBM latency.
// Now: issue loads for c+2 -> regs, compute c from LDS, land c+1's regs (issued
// one full iteration ago) into the other LDS buffer. One barrier per channel.
// CPB 32->16 halves block duration (tail reduction), grid 2048 blocks.

namespace {
constexpr int N_ = 2, C_ = 256, H_ = 128, W_ = 128;
constexpr int K_ = 5, S_ = 2, PAD_ = 2;
constexpr int SH_ = H_ * S_, SW_ = W_ * S_;          // 256, 256
constexpr int CPB = 16;                              // channels per block
constexpr int TPB = 256;
constexpr int RPB = 2;                               // source rows per block
constexpr int HB_ = H_ / RPB;                        // 64 row-blocks
constexpr int LW  = W_ + 2 * PAD_;                   // 132
constexpr int LROWS = RPB + 2 * PAD_;                // 6
constexpr int LSZ = LROWS * LW;                      // 792
constexpr int NSLOT = (LSZ + TPB - 1) / TPB;         // 4
typedef float v2f __attribute__((ext_vector_type(2)));
}

__global__ __launch_bounds__(TPB, 2) void carafe_kernel(
    const float* __restrict__ feat,
    const float* __restrict__ masks,
    float* __restrict__ out)
{
    __shared__ float lds[2][LSZ];

    const int bx = blockIdx.x;
    const int n  = bx / HB_;                  // block-uniform
    const int h0 = (bx % HB_) * RPB;
    const int t  = threadIdx.x;
    const int hl = t >> 7;                    // 0..1
    const int w  = t & (W_ - 1);
    const int h  = h0 + hl;
    const int c0 = blockIdx.y * CPB;

    // ---- staging descriptors (invariant over channels)
    int  goff[NSLOT];
    bool gval[NSLOT];
#pragma unroll
    for (int s = 0; s < NSLOT; ++s) {
        int idx = s * TPB + t;
        int r  = idx / LW, cc = idx % LW;
        int gy = h0 - PAD_ + r, gx = cc - PAD_;
        bool ok = (idx < LSZ) && ((unsigned)gy < (unsigned)H_) && ((unsigned)gx < (unsigned)W_);
        gval[s] = ok;
        goff[s] = ok ? (gy * W_ + gx) : 0;
    }

    // ---- 100 mask weights for this thread's 2x2 output quad (AGPR-resident)
    float m0[25], m1[25], m2[25], m3[25];
    {
        const float* mb = masks + ((size_t)n * 25) * (SH_ * SW_)
                                + (size_t)(S_ * h) * SW_ + S_ * w;
#pragma unroll
        for (int k = 0; k < 25; ++k) {
            v2f tt = *(const v2f*)(mb + (size_t)k * (SH_ * SW_));
            v2f bb = *(const v2f*)(mb + (size_t)k * (SH_ * SW_) + SW_);
            m0[k] = tt.x; m1[k] = tt.y; m2[k] = bb.x; m3[k] = bb.y;
        }
    }

    const float* fb = feat + ((size_t)n * C_ + c0) * (H_ * W_);
    float*       ob = out + (((size_t)n * C_ + c0) * SH_ + (size_t)(S_ * h)) * SW_ + S_ * w;

    auto issue = [&](int c, float* st) {
        const float* f = fb + (size_t)c * (H_ * W_);
#pragma unroll
        for (int s = 0; s < NSLOT; ++s) st[s] = gval[s] ? f[goff[s]] : 0.f;
    };
    auto land = [&](int b, const float* st) {
#pragma unroll
        for (int s = 0; s < NSLOT; ++s) {
            int idx = s * TPB + t;
            if (idx < LSZ) lds[b][idx] = st[s];
        }
    };
    auto compute_store = [&](const float* __restrict__ L, int c) {
        float a0 = 0.f, a1 = 0.f, a2 = 0.f, a3 = 0.f;
#pragma unroll
        for (int di = 0; di < K_; ++di) {
            const float* Lr = L + (hl + di) * LW + w;
            float f0 = Lr[0], f1 = Lr[1], f2 = Lr[2], f3 = Lr[3], f4 = Lr[4];
            const int kb = di * K_;
            a0 = fmaf(f0, m0[kb + 0], a0);
            a1 = fmaf(f0, m1[kb + 0], a1);
            a2 = fmaf(f0, m2[kb + 0], a2);
            a3 = fmaf(f0, m3[kb + 0], a3);
            a0 = fmaf(f1, m0[kb + 1], a0);
            a1 = fmaf(f1, m1[kb + 1], a1);
            a2 = fmaf(f1, m2[kb + 1], a2);
            a3 = fmaf(f1, m3[kb + 1], a3);
            a0 = fmaf(f2, m0[kb + 2], a0);
            a1 = fmaf(f2, m1[kb + 2], a1);
            a2 = fmaf(f2, m2[kb + 2], a2);
            a3 = fmaf(f2, m3[kb + 2], a3);
            a0 = fmaf(f3, m0[kb + 3], a0);
            a1 = fmaf(f3, m1[kb + 3], a1);
            a2 = fmaf(f3, m2[kb + 3], a2);
            a3 = fmaf(f3, m3[kb + 3], a3);
            a0 = fmaf(f4, m0[kb + 4], a0);
            a1 = fmaf(f4, m1[kb + 4], a1);
            a2 = fmaf(f4, m2[kb + 4], a2);
            a3 = fmaf(f4, m3[kb + 4], a3);
        }
        float* oc = ob + (size_t)c * ((size_t)SH_ * SW_);
        v2f top = {a0, a1}, bot = {a2, a3};
        __builtin_nontemporal_store(top, (v2f*)oc);
        __builtin_nontemporal_store(bot, (v2f*)(oc + SW_));
    };

    // ---- prologue: channel 0 straight into LDS[0]; channel 1 into stA
    float stA[NSLOT], stB[NSLOT];
#pragma unroll
    for (int s = 0; s < NSLOT; ++s) {
        int idx = s * TPB + t;
        if (idx < LSZ) lds[0][idx] = gval[s] ? fb[goff[s]] : 0.f;
    }
    issue(1, stA);

    for (int c2 = 0; c2 < CPB; c2 += 2) {
        // --- even channel: compute lds[0] = c2; stA holds c2+1 (in flight)
        __syncthreads();                       // lds[0] writes visible
        if (c2 + 2 < CPB) issue(c2 + 2, stB);  // 2-deep prefetch
        compute_store(&lds[0][0], c2);
        land(1, stA);                          // c2+1 -> lds[1] (vmcnt wait here)

        // --- odd channel: compute lds[1] = c2+1; stB holds c2+2 (in flight)
        __syncthreads();
        if (c2 + 3 < CPB) issue(c2 + 3, stA);
        compute_store(&lds[1][0], c2 + 1);
        if (c2 + 2 < CPB) land(0, stB);        // c2+2 -> lds[0]
    }
}

extern "C" void kernel_launch(void* const* d_in, const int* in_sizes, int n_in,
                              void* d_out, int out_size, void* d_ws, size_t ws_size,
                              hipStream_t stream) {
    const float* feat  = (const float*)d_in[0];
    const float* masks = (const float*)d_in[1];
    float* out = (float*)d_out;
    dim3 grid(N_ * HB_, C_ / CPB);            // (128, 16) = 2048 blocks
    carafe_kernel<<<grid, dim3(TPB), 0, stream>>>(feat, masks, out);
}